// Round 12
// baseline (319.021 us; speedup 1.0000x reference)
//
#include <hip/hip_runtime.h>
#include <hip/hip_bf16.h>

#define TT 512
#define II 46
#define HH 64
#define GG 192
#define CC 8
#define RR 8     // rows per block
#define KP 128   // fused K per gate: [h (64) | x (46, zero-padded to 64)]

typedef __attribute__((ext_vector_type(8))) _Float16 half8;
typedef __attribute__((ext_vector_type(2))) _Float16 half2v;
typedef __attribute__((ext_vector_type(2))) __fp16 fp16x2;
typedef __attribute__((ext_vector_type(4))) float float4v;
typedef __attribute__((ext_vector_type(2))) float float2v;

__device__ inline float fsigm(float xv) {
  return __builtin_amdgcn_rcpf(1.f + __expf(-xv));
}
// tanh(x) = 1 - 2/(1 + e^{2x}); saturates correctly at +-1, branch-free
__device__ inline float ftanh2(float xv) {
  float e = __expf(2.f * xv);
  return __builtin_fmaf(-2.f, __builtin_amdgcn_rcpf(1.f + e), 1.f);
}

// Barrier WITHOUT vmcnt drain: LDS ops fenced (lgkmcnt(0)); global x prefetches
// keep riding across barriers (consumed ~2 steps later).
__device__ inline void barrier_lds_only() {
  asm volatile("s_waitcnt lgkmcnt(0)" ::: "memory");
  __builtin_amdgcn_s_barrier();
  asm volatile("" ::: "memory");
}

// wp[u][k] f16, u in [0,192): k<64 -> w_hh[u][k]; 64<=k<110 -> w_ih[u][k-64]; else 0.
__global__ void pack_w(const float* __restrict__ w_ih, const float* __restrict__ w_hh,
                       _Float16* __restrict__ wp) {
  int idx = blockIdx.x * 256 + threadIdx.x;  // 192*128 = 24576 exact
  int u = idx >> 7, k = idx & 127;
  float v = (k < HH) ? w_hh[u * HH + k]
                     : ((k < HH + II) ? w_ih[u * II + (k - HH)] : 0.f);
  wp[idx] = (_Float16)v;
}

// Frag layout (f16): element (M-row m, k) at LDS [k>>5][((k>>3)&3)*16 + m][k&7];
// lane l=(kg,m16) reads kstep s as frag[s][l][0..7] (m = m16, k = 32s + 8kg + j).
// Batch row b at M-row (b>>1)*4+(b&1) -> {0,1,4,5,8,9,12,13}; lane's acc elems
// e=0,1 are rows {2kg, 2kg+1}. hsf (h only) double-buffered — x NEVER touches
// LDS: each lane's x-fragment is 8 consecutive floats of one row, loaded from
// global as float2 pairs 2 steps ahead and packed with v_cvt_pkrtz.
__launch_bounds__(256, 1)
__global__ void gru_main(const float* __restrict__ x,
                         const float* __restrict__ b_ih, const float* __restrict__ b_hh,
                         const float* __restrict__ fc_w, const float* __restrict__ fc_b,
                         const _Float16* __restrict__ wp,
                         float* __restrict__ out) {
  __shared__ __align__(16) _Float16 hsf[2][2][64][8];
  __shared__ float hf[RR][HH + 1];
  __shared__ float fcw[CC * HH];
  __shared__ float fcbs[CC];
  __shared__ float lgts[RR][CC];

  const int tau = threadIdx.x;
  const int w4  = tau >> 6;   // wave 0..3 (units 16*w4 .. 16*w4+15)
  const int l   = tau & 63;
  const int m16 = l & 15;
  const int kg  = l >> 4;
  const int row0 = blockIdx.x * RR;

  {
    _Float16* p = &hsf[0][0][0][0];
    for (int i = tau; i < 2 * 2 * 64 * 8; i += 256) p[i] = (_Float16)0.f;
  }

  const int u = 16 * w4 + m16;   // gate unit (output col) owned by this lane
  const float br  = b_ih[u] + b_hh[u];
  const float bz  = b_ih[64 + u] + b_hh[64 + u];
  const float bnx = b_ih[128 + u];
  const float bnh = b_hh[128 + u];

  // persistent B-fragments: h-part ksteps (k 0..63) and x-part ksteps (k 64..127)
  half8 bhr[2], bhz[2], bhn[2], bxr[2], bxz[2], bxn[2];
  {
    const _Float16* rr = wp + (size_t)u * KP + 8 * kg;
    const _Float16* rz = wp + (size_t)(64 + u) * KP + 8 * kg;
    const _Float16* rn = wp + (size_t)(128 + u) * KP + 8 * kg;
    bhr[0] = *(const half8*)(rr);      bhr[1] = *(const half8*)(rr + 32);
    bxr[0] = *(const half8*)(rr + 64); bxr[1] = *(const half8*)(rr + 96);
    bhz[0] = *(const half8*)(rz);      bhz[1] = *(const half8*)(rz + 32);
    bxz[0] = *(const half8*)(rz + 64); bxz[1] = *(const half8*)(rz + 96);
    bhn[0] = *(const half8*)(rn);      bhn[1] = *(const half8*)(rn + 32);
    bxn[0] = *(const half8*)(rn + 64); bxn[1] = *(const half8*)(rn + 96);
  }

  // h write-back coords: h[b=2kg+i] at frag (m = 4kg+i, k = u)
  const int sh  = w4 >> 1;
  const int kgp = (u >> 3) & 3;
  const int jp  = u & 7;

  // x register pipeline: lane (kg,m16) needs x[row brow][dims 8kg+j (c0) and
  // 32+8kg+j (c1, masked at d>=46)]. brow = inverse M-row map (valid when
  // (m16&3)<2; other lanes' frags stay zero -> only padding acc rows polluted).
  const int  brow = 2 * (m16 >> 2) + (m16 & 1);
  const bool bval = ((m16 & 3) < 2);
  const float* xr_ = x + (size_t)(row0 + brow) * TT * II;

  float2v P[8], Q[8], T0[8], T1[8];
#pragma unroll
  for (int j = 0; j < 8; ++j) {
    P[j] = (float2v){0.f, 0.f}; Q[j] = (float2v){0.f, 0.f};
    T0[j] = (float2v){0.f, 0.f}; T1[j] = (float2v){0.f, 0.f};
  }

  auto loadX = [&](int tt, float2v* p) {
    if (bval && tt < TT) {
      const float* base = xr_ + (size_t)tt * II;
#pragma unroll
      for (int j = 0; j < 4; ++j) {
        int d = 8 * kg + 2 * j;                 // <= 30, always valid
        p[j] = *(const float2v*)(base + d);
      }
#pragma unroll
      for (int j = 0; j < 4; ++j) {
        int d = 32 + 8 * kg + 2 * j;
        if (d + 1 < II) p[4 + j] = *(const float2v*)(base + d);
      }
    }
  };
  auto cvt2 = [](float a, float b) -> half2v {
    fp16x2 q = __builtin_amdgcn_cvt_pkrtz(a, b);
    return __builtin_bit_cast(half2v, q);
  };
  auto mkfrag = [&](const float2v* p) -> half8 {
    half2v q0 = cvt2(p[0][0], p[0][1]);
    half2v q1 = cvt2(p[1][0], p[1][1]);
    half2v q2 = cvt2(p[2][0], p[2][1]);
    half2v q3 = cvt2(p[3][0], p[3][1]);
    half8 c = {q0[0], q0[1], q1[0], q1[1], q2[0], q2[1], q3[0], q3[1]};
    return c;
  };

  float hreg[2] = {0.f, 0.f};

  __syncthreads();               // hsf zero-init fence

  // prologue: frags for x(0) -> xaccA; frags for x(1) -> fC; P=x(2), Q=x(3)
  loadX(0, T0);
  loadX(1, T1);
  half8 g0 = mkfrag(T0), g1 = mkfrag(T0 + 4);
  half8 fC0 = mkfrag(T1), fC1 = mkfrag(T1 + 4);
  half8 fD0 = fC0, fD1 = fC1;
  float4v xrA = {br, br, br, br}, xzA = {bz, bz, bz, bz}, xnA = {bnx, bnx, bnx, bnx};
  xrA = __builtin_amdgcn_mfma_f32_16x16x32_f16(g0, bxr[0], xrA, 0, 0, 0);
  xzA = __builtin_amdgcn_mfma_f32_16x16x32_f16(g0, bxz[0], xzA, 0, 0, 0);
  xnA = __builtin_amdgcn_mfma_f32_16x16x32_f16(g0, bxn[0], xnA, 0, 0, 0);
  xrA = __builtin_amdgcn_mfma_f32_16x16x32_f16(g1, bxr[1], xrA, 0, 0, 0);
  xzA = __builtin_amdgcn_mfma_f32_16x16x32_f16(g1, bxz[1], xzA, 0, 0, 0);
  xnA = __builtin_amdgcn_mfma_f32_16x16x32_f16(g1, bxn[1], xnA, 0, 0, 0);
  float4v xrB, xzB, xnB;
  loadX(2, P);
  loadX(3, Q);

  // One step. cur compile-time (unroll-by-2). xC = x-part accs for t (ready);
  // xN = x-part accs for t+1 (made here from frags fu); frags fm for t+2 are
  // packed from pending floats, which are then re-loaded with x(t+4).
  auto iter = [&](int t, int cur,
                  float4v& xrC, float4v& xzC, float4v& xnC,
                  float4v& xrN, float4v& xzN, float4v& xnN,
                  half8& fu0, half8& fu1, half8& fm0, half8& fm1,
                  float2v* pend) {
    barrier_lds_only();          // h(t) in hsf[cur] visible
    const int nxt = cur ^ 1;
    half8 a0 = *(const half8*)&hsf[cur][0][l][0];
    half8 a1 = *(const half8*)&hsf[cur][1][l][0];

    // critical: h-GEMM, C-init = x-part accs (biases included)
    float4v nh4 = {bnh, bnh, bnh, bnh};
    float4v accr  = __builtin_amdgcn_mfma_f32_16x16x32_f16(a0, bhr[0], xrC, 0, 0, 0);
    float4v accz  = __builtin_amdgcn_mfma_f32_16x16x32_f16(a0, bhz[0], xzC, 0, 0, 0);
    float4v accnh = __builtin_amdgcn_mfma_f32_16x16x32_f16(a0, bhn[0], nh4, 0, 0, 0);
    accr  = __builtin_amdgcn_mfma_f32_16x16x32_f16(a1, bhr[1], accr, 0, 0, 0);
    accz  = __builtin_amdgcn_mfma_f32_16x16x32_f16(a1, bhz[1], accz, 0, 0, 0);
    accnh = __builtin_amdgcn_mfma_f32_16x16x32_f16(a1, bhn[1], accnh, 0, 0, 0);

    // off-critical: x-part for t+1 from register frags
    xrN = (float4v){br, br, br, br};
    xzN = (float4v){bz, bz, bz, bz};
    xnN = (float4v){bnx, bnx, bnx, bnx};
    xrN = __builtin_amdgcn_mfma_f32_16x16x32_f16(fu0, bxr[0], xrN, 0, 0, 0);
    xzN = __builtin_amdgcn_mfma_f32_16x16x32_f16(fu0, bxz[0], xzN, 0, 0, 0);
    xnN = __builtin_amdgcn_mfma_f32_16x16x32_f16(fu0, bxn[0], xnN, 0, 0, 0);
    xrN = __builtin_amdgcn_mfma_f32_16x16x32_f16(fu1, bxr[1], xrN, 0, 0, 0);
    xzN = __builtin_amdgcn_mfma_f32_16x16x32_f16(fu1, bxz[1], xzN, 0, 0, 0);
    xnN = __builtin_amdgcn_mfma_f32_16x16x32_f16(fu1, bxn[1], xnN, 0, 0, 0);

    // pack x(t+2) frags (vmcnt wait lands here, ~2 steps of slack), reload pend
    fm0 = mkfrag(pend);
    fm1 = mkfrag(pend + 4);
    loadX(t + 4, pend);

    // gates (critical)
#pragma unroll
    for (int i = 0; i < 2; ++i) {
      float rg = fsigm(accr[i]);
      float zg = fsigm(accz[i]);
      float pre = __builtin_fmaf(rg, accnh[i], xnC[i]);
      float ng = ftanh2(pre);
      hreg[i] = __builtin_fmaf(zg, hreg[i] - ng, ng);
      hsf[nxt][sh][kgp * 16 + kg * 4 + i][jp] = (_Float16)hreg[i];
    }
  };

  for (int t = 0; t < TT; t += 2) {
    iter(t,     0, xrA, xzA, xnA, xrB, xzB, xnB, fC0, fC1, fD0, fD1, P);
    iter(t + 1, 1, xrB, xzB, xnB, xrA, xzA, xnA, fD0, fD1, fC0, fC1, Q);
  }

  // ================= Epilogue: FC + softmax =================
  hf[2 * kg + 0][u] = hreg[0];
  hf[2 * kg + 1][u] = hreg[1];
  fcw[tau] = fc_w[tau];
  fcw[tau + 256] = fc_w[tau + 256];
  if (tau < CC) fcbs[tau] = fc_b[tau];
  __syncthreads();
  if (tau < RR * CC) {
    int rr = tau >> 3, c = tau & 7;
    float acc = fcbs[c];
#pragma unroll
    for (int j = 0; j < HH; ++j) acc += hf[rr][j] * fcw[c * HH + j];
    lgts[rr][c] = acc;
  }
  __syncthreads();
  if (tau < RR * CC) {
    int rr = tau >> 3, c = tau & 7;
    float mx = lgts[rr][0];
#pragma unroll
    for (int j = 1; j < CC; ++j) mx = fmaxf(mx, lgts[rr][j]);
    float ssum = 0.f;
#pragma unroll
    for (int j = 0; j < CC; ++j) ssum += __expf(lgts[rr][j] - mx);
    out[(size_t)(row0 + rr) * CC + c] = __expf(lgts[rr][c] - mx) / ssum;
  }
}

extern "C" void kernel_launch(void* const* d_in, const int* in_sizes, int n_in,
                              void* d_out, int out_size, void* d_ws, size_t ws_size,
                              hipStream_t stream) {
  const float* x    = (const float*)d_in[0];
  const float* w_ih = (const float*)d_in[1];
  const float* w_hh = (const float*)d_in[2];
  const float* b_ih = (const float*)d_in[3];
  const float* b_hh = (const float*)d_in[4];
  const float* fc_w = (const float*)d_in[5];
  const float* fc_b = (const float*)d_in[6];

  _Float16* wp = (_Float16*)d_ws;  // 192*128 f16 = 48 KiB

  pack_w<<<96, 256, 0, stream>>>(w_ih, w_hh, wp);
  gru_main<<<256, 256, 0, stream>>>(x, b_ih, b_hh, fc_w, fc_b, wp, (float*)d_out);
}

// Round 13
// 274.317 us; speedup vs baseline: 1.1630x; 1.1630x over previous
//
#include <hip/hip_runtime.h>
#include <hip/hip_bf16.h>

#define TT 512
#define II 46
#define HH 64
#define GG 192
#define CC 8
#define RR 8     // rows per block
#define KP 128   // fused K per gate: [h (64) | x (46, zero-padded to 64)]

typedef __attribute__((ext_vector_type(8))) _Float16 half8;
typedef __attribute__((ext_vector_type(4))) float float4v;

__device__ inline float fsigm(float xv) {
  return __builtin_amdgcn_rcpf(1.f + __expf(-xv));
}
// tanh(x) = 1 - 2/(1 + e^{2x}); saturates correctly at +-1, branch-free
__device__ inline float ftanh2(float xv) {
  float e = __expf(2.f * xv);
  return __builtin_fmaf(-2.f, __builtin_amdgcn_rcpf(1.f + e), 1.f);
}

// Barrier WITHOUT vmcnt drain: LDS ops fenced (lgkmcnt(0)); global x prefetches
// ride across barriers (consumed ~2 steps later).
__device__ inline void barrier_lds_only() {
  asm volatile("s_waitcnt lgkmcnt(0)" ::: "memory");
  __builtin_amdgcn_s_barrier();
  asm volatile("" ::: "memory");
}

// wp[u][k] f16, u in [0,192): k<64 -> w_hh[u][k]; 64<=k<110 -> w_ih[u][k-64]; else 0.
__global__ void pack_w(const float* __restrict__ w_ih, const float* __restrict__ w_hh,
                       _Float16* __restrict__ wp) {
  int idx = blockIdx.x * 256 + threadIdx.x;  // 192*128 = 24576 exact
  int u = idx >> 7, k = idx & 127;
  float v = (k < HH) ? w_hh[u * HH + k]
                     : ((k < HH + II) ? w_ih[u * II + (k - HH)] : 0.f);
  wp[idx] = (_Float16)v;
}

// Frag layout (f16): element (M-row m, k) at LDS [k>>5][((k>>3)&3)*16 + m][k&7].
// h tile: batch row b at M-row (b>>1)*4+(b&1) (e=0,1 of lane (kg,m16) = rows
// {2kg,2kg+1}). x PAIR tile (pair j = steps 2j,2j+1): step 2j rows at the same
// M-rows (acc e=0,1), step 2j+1 rows at +2 (acc e=2,3) — ONE set of 6 x-MFMAs
// covers TWO timesteps. xsf double-buffered by pair parity; pair p staged at
// step 2p-4, x-MFMA'd at step 2p-1, consumed at steps 2p (e01) / 2p+1 (e23).
__launch_bounds__(256, 1)
__global__ void gru_main(const float* __restrict__ x,
                         const float* __restrict__ b_ih, const float* __restrict__ b_hh,
                         const float* __restrict__ fc_w, const float* __restrict__ fc_b,
                         const _Float16* __restrict__ wp,
                         float* __restrict__ out) {
  __shared__ __align__(16) _Float16 hsf[2][2][64][8];
  __shared__ __align__(16) _Float16 xsf[2][2][64][8];
  __shared__ float hf[RR][HH + 1];
  __shared__ float fcw[CC * HH];
  __shared__ float fcbs[CC];
  __shared__ float lgts[RR][CC];

  const int tau = threadIdx.x;
  const int w4  = tau >> 6;   // wave 0..3 (units 16*w4 .. 16*w4+15)
  const int l   = tau & 63;
  const int m16 = l & 15;
  const int kg  = l >> 4;
  const int row0 = blockIdx.x * RR;

  {
    _Float16* p = &hsf[0][0][0][0];
    for (int i = tau; i < 2 * 2 * 64 * 8; i += 256) p[i] = (_Float16)0.f;
    p = &xsf[0][0][0][0];
    for (int i = tau; i < 2 * 2 * 64 * 8; i += 256) p[i] = (_Float16)0.f;
  }
  __syncthreads();   // zero-init fence BEFORE any staging (fixes latent race)

  const int u = 16 * w4 + m16;   // gate unit owned by this lane
  const float br  = b_ih[u] + b_hh[u];
  const float bz  = b_ih[64 + u] + b_hh[64 + u];
  const float bnx = b_ih[128 + u];
  const float bnh = b_hh[128 + u];

  // persistent B-fragments: h-part (k 0..63) and x-part (k 64..127)
  half8 bhr[2], bhz[2], bhn[2], bxr[2], bxz[2], bxn[2];
  {
    const _Float16* rr = wp + (size_t)u * KP + 8 * kg;
    const _Float16* rz = wp + (size_t)(64 + u) * KP + 8 * kg;
    const _Float16* rn = wp + (size_t)(128 + u) * KP + 8 * kg;
    bhr[0] = *(const half8*)(rr);      bhr[1] = *(const half8*)(rr + 32);
    bxr[0] = *(const half8*)(rr + 64); bxr[1] = *(const half8*)(rr + 96);
    bhz[0] = *(const half8*)(rz);      bhz[1] = *(const half8*)(rz + 32);
    bxz[0] = *(const half8*)(rz + 64); bxz[1] = *(const half8*)(rz + 96);
    bhn[0] = *(const half8*)(rn);      bhn[1] = *(const half8*)(rn + 32);
    bxn[0] = *(const half8*)(rn + 64); bxn[1] = *(const half8*)(rn + 96);
  }

  const int sh  = w4 >> 1;
  const int kgp = (u >> 3) & 3;
  const int jp  = u & 7;

  // pair-slab staging: 16x46 = 736 elems (sigma=step-in-pair, b, i);
  // thread owns elems tau, tau+256, tau+512. M-row = (b>>1)*4+(b&1)+2*sigma.
  bool ev_[3]; int es_[3], eln[3], ej_[3];
  const float* ep_[3];
#pragma unroll
  for (int q = 0; q < 3; ++q) {
    int e = tau + 256 * q;
    ev_[q] = e < 2 * RR * II;
    int e2 = ev_[q] ? e : 0;
    int sg = (e2 >= RR * II) ? 1 : 0;
    int rem = e2 - RR * II * sg;
    int b = rem / II, i = rem % II;
    es_[q] = i >> 5;
    eln[q] = ((i >> 3) & 3) * 16 + (b >> 1) * 4 + (b & 1) + 2 * sg;
    ej_[q] = i & 7;
    ep_[q] = x + (size_t)(row0 + b) * TT * II + (size_t)sg * II + i; // +2j*II per pair
  }

  float hreg[2] = {0.f, 0.f};

  // prologue: load pairs 0,1,2; stage pairs 0,1
  float pA[3], pB[3];
  {
    float pd0[3], pd1[3];
#pragma unroll
    for (int q = 0; q < 3; ++q) {
      pd0[q] = ev_[q] ? ep_[q][0] : 0.f;
      pd1[q] = ev_[q] ? ep_[q][2 * II] : 0.f;
      pA[q]  = ev_[q] ? ep_[q][4 * II] : 0.f;     // pair 2, staged at step 0
    }
#pragma unroll
    for (int q = 0; q < 3; ++q) if (ev_[q]) xsf[0][es_[q]][eln[q]][ej_[q]] = (_Float16)pd0[q];
#pragma unroll
    for (int q = 0; q < 3; ++q) if (ev_[q]) xsf[1][es_[q]][eln[q]][ej_[q]] = (_Float16)pd1[q];
  }
  __syncthreads();   // staging of pairs 0,1 visible

  auto xm = [&](const half8& c0, const half8& c1,
                float4v& xr, float4v& xz, float4v& xn) {
    xr = (float4v){br, br, br, br};
    xz = (float4v){bz, bz, bz, bz};
    xn = (float4v){bnx, bnx, bnx, bnx};
    xr = __builtin_amdgcn_mfma_f32_16x16x32_f16(c0, bxr[0], xr, 0, 0, 0);
    xz = __builtin_amdgcn_mfma_f32_16x16x32_f16(c0, bxz[0], xz, 0, 0, 0);
    xn = __builtin_amdgcn_mfma_f32_16x16x32_f16(c0, bxn[0], xn, 0, 0, 0);
    xr = __builtin_amdgcn_mfma_f32_16x16x32_f16(c1, bxr[1], xr, 0, 0, 0);
    xz = __builtin_amdgcn_mfma_f32_16x16x32_f16(c1, bxz[1], xz, 0, 0, 0);
    xn = __builtin_amdgcn_mfma_f32_16x16x32_f16(c1, bxn[1], xn, 0, 0, 0);
  };

  float4v xrA, xzA, xnA, xrB, xzB, xnB;
  {  // x-accs for pair 0 (steps 0,1)
    half8 c0 = *(const half8*)&xsf[0][0][l][0];
    half8 c1 = *(const half8*)&xsf[0][1][l][0];
    xm(c0, c1, xrA, xzA, xnA);
  }

  // running global pointers: next load is pair 3
  const float* pp0 = ep_[0] + 6 * II;
  const float* pp1 = ep_[1] + 6 * II;
  const float* pp2 = ep_[2] + 6 * II;

  // h-GEMM + gates for one step. cr/cz carry the x-part (+biases) at e01.
  auto hcore = [&](int cur, float4v cr, float4v cz, float xn0, float xn1) {
    half8 a0 = *(const half8*)&hsf[cur][0][l][0];
    half8 a1 = *(const half8*)&hsf[cur][1][l][0];
    float4v nh4 = {bnh, bnh, bnh, bnh};
    float4v ar = __builtin_amdgcn_mfma_f32_16x16x32_f16(a0, bhr[0], cr, 0, 0, 0);
    float4v az = __builtin_amdgcn_mfma_f32_16x16x32_f16(a0, bhz[0], cz, 0, 0, 0);
    float4v an = __builtin_amdgcn_mfma_f32_16x16x32_f16(a0, bhn[0], nh4, 0, 0, 0);
    ar = __builtin_amdgcn_mfma_f32_16x16x32_f16(a1, bhr[1], ar, 0, 0, 0);
    az = __builtin_amdgcn_mfma_f32_16x16x32_f16(a1, bhz[1], az, 0, 0, 0);
    an = __builtin_amdgcn_mfma_f32_16x16x32_f16(a1, bhn[1], an, 0, 0, 0);
    const int nxt = cur ^ 1;
    float rg0 = fsigm(ar[0]), zg0 = fsigm(az[0]);
    float rg1 = fsigm(ar[1]), zg1 = fsigm(az[1]);
    float ng0 = ftanh2(__builtin_fmaf(rg0, an[0], xn0));
    float ng1 = ftanh2(__builtin_fmaf(rg1, an[1], xn1));
    hreg[0] = __builtin_fmaf(zg0, hreg[0] - ng0, ng0);
    hreg[1] = __builtin_fmaf(zg1, hreg[1] - ng1, ng1);
    hsf[nxt][sh][kgp * 16 + kg * 4 + 0][jp] = (_Float16)hreg[0];
    hsf[nxt][sh][kgp * 16 + kg * 4 + 1][jp] = (_Float16)hreg[1];
  };

  for (int q = 0; q < TT / 4; ++q) {
    const int j0 = 2 * q;            // pairs j0, j0+1; steps 4q..4q+3
    // ---- step 4q (even): pair j0 e01; stage pair j0+2; load pair j0+3 ----
    barrier_lds_only();
#pragma unroll
    for (int s3 = 0; s3 < 3; ++s3)
      if (ev_[s3]) xsf[0][es_[s3]][eln[s3]][ej_[s3]] = (_Float16)pA[s3];
    {
      const bool ok = (j0 + 3) < TT / 2;
      pB[0] = (ev_[0] && ok) ? pp0[0] : 0.f;
      pB[1] = (ev_[1] && ok) ? pp1[0] : 0.f;
      pB[2] = (ev_[2] && ok) ? pp2[0] : 0.f;
      pp0 += 2 * II; pp1 += 2 * II; pp2 += 2 * II;
    }
    hcore(0, xrA, xzA, xnA[0], xnA[1]);

    // ---- step 4q+1 (odd): pair j0 e23; x-MFMA pair j0+1 -> B ----
    barrier_lds_only();
    {
      half8 c0 = *(const half8*)&xsf[1][0][l][0];
      half8 c1 = *(const half8*)&xsf[1][1][l][0];
      float4v cr = __builtin_shufflevector(xrA, xrA, 2, 3, 2, 3);
      float4v cz = __builtin_shufflevector(xzA, xzA, 2, 3, 2, 3);
      hcore(1, cr, cz, xnA[2], xnA[3]);
      xm(c0, c1, xrB, xzB, xnB);
    }

    // ---- step 4q+2 (even): pair j0+1 e01; stage pair j0+3; load pair j0+4 ----
    barrier_lds_only();
#pragma unroll
    for (int s3 = 0; s3 < 3; ++s3)
      if (ev_[s3]) xsf[1][es_[s3]][eln[s3]][ej_[s3]] = (_Float16)pB[s3];
    {
      const bool ok = (j0 + 4) < TT / 2;
      pA[0] = (ev_[0] && ok) ? pp0[0] : 0.f;
      pA[1] = (ev_[1] && ok) ? pp1[0] : 0.f;
      pA[2] = (ev_[2] && ok) ? pp2[0] : 0.f;
      pp0 += 2 * II; pp1 += 2 * II; pp2 += 2 * II;
    }
    hcore(0, xrB, xzB, xnB[0], xnB[1]);

    // ---- step 4q+3 (odd): pair j0+1 e23; x-MFMA pair j0+2 -> A ----
    barrier_lds_only();
    {
      half8 c0 = *(const half8*)&xsf[0][0][l][0];
      half8 c1 = *(const half8*)&xsf[0][1][l][0];
      float4v cr = __builtin_shufflevector(xrB, xrB, 2, 3, 2, 3);
      float4v cz = __builtin_shufflevector(xzB, xzB, 2, 3, 2, 3);
      hcore(1, cr, cz, xnB[2], xnB[3]);
      xm(c0, c1, xrA, xzA, xnA);
    }
  }

  // ================= Epilogue: FC + softmax =================
  hf[2 * kg + 0][u] = hreg[0];
  hf[2 * kg + 1][u] = hreg[1];
  fcw[tau] = fc_w[tau];
  fcw[tau + 256] = fc_w[tau + 256];
  if (tau < CC) fcbs[tau] = fc_b[tau];
  __syncthreads();
  if (tau < RR * CC) {
    int rr = tau >> 3, c = tau & 7;
    float acc = fcbs[c];
#pragma unroll
    for (int j = 0; j < HH; ++j) acc += hf[rr][j] * fcw[c * HH + j];
    lgts[rr][c] = acc;
  }
  __syncthreads();
  if (tau < RR * CC) {
    int rr = tau >> 3, c = tau & 7;
    float mx = lgts[rr][0];
#pragma unroll
    for (int j = 1; j < CC; ++j) mx = fmaxf(mx, lgts[rr][j]);
    float ssum = 0.f;
#pragma unroll
    for (int j = 0; j < CC; ++j) ssum += __expf(lgts[rr][j] - mx);
    out[(size_t)(row0 + rr) * CC + c] = __expf(lgts[rr][c] - mx) / ssum;
  }
}

extern "C" void kernel_launch(void* const* d_in, const int* in_sizes, int n_in,
                              void* d_out, int out_size, void* d_ws, size_t ws_size,
                              hipStream_t stream) {
  const float* x    = (const float*)d_in[0];
  const float* w_ih = (const float*)d_in[1];
  const float* w_hh = (const float*)d_in[2];
  const float* b_ih = (const float*)d_in[3];
  const float* b_hh = (const float*)d_in[4];
  const float* fc_w = (const float*)d_in[5];
  const float* fc_b = (const float*)d_in[6];

  _Float16* wp = (_Float16*)d_ws;  // 192*128 f16 = 48 KiB

  pack_w<<<96, 256, 0, stream>>>(w_ih, w_hh, wp);
  gru_main<<<256, 256, 0, stream>>>(x, b_ih, b_hh, fc_w, fc_b, wp, (float*)d_out);
}